// Round 1
// baseline (301.387 us; speedup 1.0000x reference)
//
#include <hip/hip_runtime.h>

typedef float f32x4 __attribute__((ext_vector_type(4)));
typedef __bf16 bf16x8 __attribute__((ext_vector_type(8)));

__device__ __forceinline__ unsigned short f2bf(float f) {
  unsigned u = __float_as_uint(f);
  unsigned r = (u + 0x7fffu + ((u >> 16) & 1u)) >> 16;
  return (unsigned short)r;
}
__device__ __forceinline__ float bf2f(unsigned short h) {
  return __uint_as_float(((unsigned)h) << 16);
}

// ---------------- fp32 -> bf16 conversion ----------------
__global__ __launch_bounds__(256) void k_cvt(const float* __restrict__ in,
                                             unsigned short* __restrict__ out, int n4) {
  int i = blockIdx.x * 256 + threadIdx.x;
  if (i < n4) {
    float4 v = ((const float4*)in)[i];
    ushort4 o;
    o.x = f2bf(v.x); o.y = f2bf(v.y); o.z = f2bf(v.z); o.w = f2bf(v.w);
    ((ushort4*)out)[i] = o;
  }
}

// ---------------- softmax over freq_w[513] ----------------
__global__ __launch_bounds__(256) void k_softmax(const float* __restrict__ fw,
                                                 float* __restrict__ wspec) {
  __shared__ float red[4];
  int tid = threadIdx.x;
  float m = -1e30f;
  for (int i = tid; i < 513; i += 256) m = fmaxf(m, fw[i]);
  #pragma unroll
  for (int o = 32; o; o >>= 1) m = fmaxf(m, __shfl_down(m, o));
  if ((tid & 63) == 0) red[tid >> 6] = m;
  __syncthreads();
  m = fmaxf(fmaxf(red[0], red[1]), fmaxf(red[2], red[3]));
  float s = 0.f;
  for (int i = tid; i < 513; i += 256) s += expf(fw[i] - m);
  #pragma unroll
  for (int o = 32; o; o >>= 1) s += __shfl_down(s, o);
  __syncthreads();
  if ((tid & 63) == 0) red[tid >> 6] = s;
  __syncthreads();
  s = red[0] + red[1] + red[2] + red[3];
  float inv = 1.f / s;
  for (int i = tid; i < 513; i += 256) wspec[i] = expf(fw[i] - m) * inv;
}

// ---------------- bf16 MFMA GEMM: C[m,n] = sum_k A[m,k]*B[n,k] ----------------
// M=8192 (grid.y*128... 1D grid: bid>>3), N=1024 (bid&7), K=1024.
// MODE 0: silu -> bf16 store.  MODE 1: *scale -> fp32 store.
template <int MODE>
__global__ __launch_bounds__(256) void k_gemm(const unsigned short* __restrict__ A,
                                              const unsigned short* __restrict__ B,
                                              void* __restrict__ Cout,
                                              const float* __restrict__ scale_ptr) {
  __shared__ __align__(16) unsigned short As[128 * 64];
  __shared__ __align__(16) unsigned short Bs[128 * 64];
  const int tid = threadIdx.x;
  const int lane = tid & 63;
  const int wave = tid >> 6;
  const int bm = (blockIdx.x >> 3) * 128;
  const int bn = (blockIdx.x & 7) * 128;
  const int mhalf = (wave & 1) * 64;
  const int nhalf = (wave >> 1) * 64;
  f32x4 acc[4][4] = {};

  const int ar = tid >> 3;        // row within a 32-row staging round
  const int ac = (tid & 7) * 8;   // bf16 element offset within row
  const unsigned short* Abase = A + (size_t)(bm + ar) * 1024 + ac;
  const unsigned short* Bbase = B + (size_t)(bn + ar) * 1024 + ac;
  char* AsB = (char*)As;
  char* BsB = (char*)Bs;

  for (int kt = 0; kt < 16; ++kt) {
    const int k0 = kt * 64;
    #pragma unroll
    for (int r = 0; r < 4; ++r) {
      __builtin_amdgcn_global_load_lds(
          (const __attribute__((address_space(1))) void*)(Abase + (size_t)(r * 32) * 1024 + k0),
          (__attribute__((address_space(3))) void*)(AsB + r * 4096 + wave * 1024), 16, 0, 0);
      __builtin_amdgcn_global_load_lds(
          (const __attribute__((address_space(1))) void*)(Bbase + (size_t)(r * 32) * 1024 + k0),
          (__attribute__((address_space(3))) void*)(BsB + r * 4096 + wave * 1024), 16, 0, 0);
    }
    __syncthreads();
    const int mrow = lane & 15;
    const int kq = lane >> 4;
    #pragma unroll
    for (int kc = 0; kc < 2; ++kc) {
      bf16x8 af[4], bfr[4];
      #pragma unroll
      for (int mt = 0; mt < 4; ++mt)
        af[mt] = *(const bf16x8*)(AsB + (mhalf + mt * 16 + mrow) * 128 + kc * 64 + kq * 16);
      #pragma unroll
      for (int nt = 0; nt < 4; ++nt)
        bfr[nt] = *(const bf16x8*)(BsB + (nhalf + nt * 16 + mrow) * 128 + kc * 64 + kq * 16);
      #pragma unroll
      for (int mt = 0; mt < 4; ++mt)
        #pragma unroll
        for (int nt = 0; nt < 4; ++nt)
          acc[mt][nt] = __builtin_amdgcn_mfma_f32_16x16x32_bf16(af[mt], bfr[nt], acc[mt][nt], 0, 0, 0);
    }
    __syncthreads();
  }

  const float scl = (MODE == 1) ? scale_ptr[0] : 0.f;
  const int col = bn + nhalf + (lane & 15);
  const int rbase = bm + mhalf + (lane >> 4) * 4;
  #pragma unroll
  for (int mt = 0; mt < 4; ++mt)
    #pragma unroll
    for (int nt = 0; nt < 4; ++nt)
      #pragma unroll
      for (int r = 0; r < 4; ++r) {
        float v = acc[mt][nt][r];
        size_t idx = (size_t)(rbase + mt * 16 + r) * 1024 + (col + nt * 16);
        if (MODE == 0) {
          float sv = v / (1.f + expf(-v));
          ((unsigned short*)Cout)[idx] = f2bf(sv);
        } else {
          ((float*)Cout)[idx] = v * scl;
        }
      }
}

// ---------------- block reduction helper ----------------
__device__ __forceinline__ float blk_sum(float v, float* red, int tid) {
  #pragma unroll
  for (int o = 32; o; o >>= 1) v += __shfl_down(v, o);
  __syncthreads();
  if ((tid & 63) == 0) red[tid >> 6] = v;
  __syncthreads();
  return red[0] + red[1] + red[2] + red[3];
}

// ---------------- fused LayerNorm + spectral filter (FFT) + Poincare scale ----------------
// one block per row of 1024; 256 threads
__global__ __launch_bounds__(256) void k_lnfft(const unsigned short* __restrict__ comp,
                                               const float* __restrict__ ln_g,
                                               const float* __restrict__ ln_b,
                                               const float* __restrict__ wspec,
                                               const float* __restrict__ t_ptr,
                                               unsigned short* __restrict__ hyp) {
  __shared__ __align__(16) float re[1024];
  __shared__ __align__(16) float im[1024];
  __shared__ float twr[512];
  __shared__ float twi[512];
  __shared__ float wsh[513];
  __shared__ float red[4];
  const int tid = threadIdx.x;
  const size_t rowoff = (size_t)blockIdx.x * 1024;

  // load bf16 comp row into registers
  ushort4 cv = ((const ushort4*)(comp + rowoff))[tid];
  float x0 = bf2f(cv.x), x1 = bf2f(cv.y), x2 = bf2f(cv.z), x3 = bf2f(cv.w);

  // twiddles exp(-2*pi*i*j/1024) and spectral weights into LDS
  for (int j = tid; j < 512; j += 256) {
    float s, c;
    sincosf(-6.283185307179586f * (float)j * (1.f / 1024.f), &s, &c);
    twr[j] = c; twi[j] = s;
  }
  for (int j = tid; j < 513; j += 256) wsh[j] = wspec[j];

  // LayerNorm (two-pass)
  float mu = blk_sum(x0 + x1 + x2 + x3, red, tid) * (1.f / 1024.f);
  float d0 = x0 - mu, d1 = x1 - mu, d2 = x2 - mu, d3 = x3 - mu;
  float var = blk_sum(d0 * d0 + d1 * d1 + d2 * d2 + d3 * d3, red, tid) * (1.f / 1024.f);
  float inv = rsqrtf(var + 1e-5f);
  float4 g = ((const float4*)ln_g)[tid];
  float4 b = ((const float4*)ln_b)[tid];
  float4 nv;
  nv.x = d0 * inv * g.x + b.x;
  nv.y = d1 * inv * g.y + b.y;
  nv.z = d2 * inv * g.z + b.z;
  nv.w = d3 * inv * g.w + b.w;
  ((float4*)re)[tid] = nv;
  float4 z4; z4.x = 0.f; z4.y = 0.f; z4.z = 0.f; z4.w = 0.f;
  ((float4*)im)[tid] = z4;
  __syncthreads();

  // forward FFT, DIF (natural in -> bit-reversed out)
  for (int lh = 9; lh >= 0; --lh) {
    const int half = 1 << lh;
    const int tstep = 512 >> lh;
    for (int b2 = tid; b2 < 512; b2 += 256) {
      int j = b2 & (half - 1);
      int i0 = ((b2 >> lh) << (lh + 1)) + j;
      int i1 = i0 + half;
      float ur = re[i0], ui = im[i0], vr = re[i1], vi = im[i1];
      re[i0] = ur + vr; im[i0] = ui + vi;
      float dr = ur - vr, di = ui - vi;
      float wr = twr[j * tstep], wi = twi[j * tstep];
      re[i1] = dr * wr - di * wi;
      im[i1] = dr * wi + di * wr;
    }
    __syncthreads();
  }

  // spectral weights at bit-reversed positions (1/N folded in)
  #pragma unroll
  for (int q = 0; q < 4; ++q) {
    int p = tid + q * 256;
    int f = __brev((unsigned)p) >> 22;
    int fs = (f <= 512) ? f : 1024 - f;
    float s = wsh[fs] * (1.f / 1024.f);
    re[p] *= s; im[p] *= s;
  }
  __syncthreads();

  // inverse FFT, DIT (bit-reversed in -> natural out)
  for (int lh = 0; lh <= 9; ++lh) {
    const int half = 1 << lh;
    const int tstep = 512 >> lh;
    for (int b2 = tid; b2 < 512; b2 += 256) {
      int j = b2 & (half - 1);
      int i0 = ((b2 >> lh) << (lh + 1)) + j;
      int i1 = i0 + half;
      float wr = twr[j * tstep], wi = -twi[j * tstep];
      float xr = re[i1], xi = im[i1];
      float tr = xr * wr - xi * wi, ti = xr * wi + xi * wr;
      float ur = re[i0], ui = im[i0];
      re[i0] = ur + tr; im[i0] = ui + ti;
      re[i1] = ur - tr; im[i1] = ui - ti;
    }
    __syncthreads();
  }

  // flat row is in re[]; Poincare layer collapses to hyp = gamma * flat
  float f0 = re[tid * 4 + 0], f1 = re[tid * 4 + 1], f2 = re[tid * 4 + 2], f3 = re[tid * 4 + 3];
  float U2 = blk_sum(f0 * f0 + f1 * f1 + f2 * f2 + f3 * f3, red, tid);

  const float tv = t_ptr[0];
  const float sc = 0.01f;      // sqrt(1e-4)
  const float c = 1e-4f;
  float nrm = sqrtf(U2);
  float nu = fmaxf(nrm, 1e-7f);
  float su = fminf(fmaxf(sc * nu, 1e-7f), 1.f - 1e-5f);
  float Af = tanhf((1.f - tv) * atanhf(su)) / (sc * nu);
  float nvn = fmaxf(fabsf(tv) * nrm, 1e-7f);
  float svv = fminf(fmaxf(sc * nvn, 1e-7f), 1.f - 1e-5f);
  float Bf = tv * tanhf(tv * atanhf(svv)) / (sc * nvn);
  float x2s = Af * Af * U2, y2s = Bf * Bf * U2, xys = Af * Bf * U2;
  float numc = (1.f + 2.f * c * xys + c * y2s) * Af + (1.f - c * x2s) * Bf;
  float den = fmaxf(1.f + 2.f * c * xys + c * c * x2s * y2s, 1e-7f);
  float gam = numc / den;

  ushort4 o;
  o.x = f2bf(gam * f0); o.y = f2bf(gam * f1); o.z = f2bf(gam * f2); o.w = f2bf(gam * f3);
  ((ushort4*)(hyp + rowoff))[tid] = o;
}

extern "C" void kernel_launch(void* const* d_in, const int* in_sizes, int n_in,
                              void* d_out, int out_size, void* d_ws, size_t ws_size,
                              hipStream_t stream) {
  const float* x      = (const float*)d_in[0];
  const float* proj_w = (const float*)d_in[1];
  const float* ln_g   = (const float*)d_in[2];
  const float* ln_b   = (const float*)d_in[3];
  const float* freq_w = (const float*)d_in[4];
  const float* t_p    = (const float*)d_in[5];
  const float* down_w = (const float*)d_in[6];
  const float* scale  = (const float*)d_in[7];

  char* ws = (char*)d_ws;
  unsigned short* xb   = (unsigned short*)ws;                         // 16 MB (reused for hyp)
  unsigned short* pwb  = (unsigned short*)(ws + 16777216);            // 2 MB
  unsigned short* dwb  = (unsigned short*)(ws + 18874368);            // 2 MB
  unsigned short* comp = (unsigned short*)(ws + 20971520);            // 16 MB
  float* wspec         = (float*)(ws + 37748736);                     // 4 KB
  unsigned short* hypb = xb;  // x no longer needed after GEMM1

  k_softmax<<<1, 256, 0, stream>>>(freq_w, wspec);
  k_cvt<<<8192, 256, 0, stream>>>(x, xb, 2097152);
  k_cvt<<<1024, 256, 0, stream>>>(proj_w, pwb, 262144);
  k_cvt<<<1024, 256, 0, stream>>>(down_w, dwb, 262144);
  k_gemm<0><<<512, 256, 0, stream>>>(xb, pwb, (void*)comp, nullptr);
  k_lnfft<<<8192, 256, 0, stream>>>(comp, ln_g, ln_b, wspec, t_p, hypb);
  k_gemm<1><<<512, 256, 0, stream>>>(hypb, dwb, d_out, scale);
}

// Round 2
// 227.068 us; speedup vs baseline: 1.3273x; 1.3273x over previous
//
#include <hip/hip_runtime.h>

typedef float f32x4 __attribute__((ext_vector_type(4)));
typedef __bf16 bf16x8 __attribute__((ext_vector_type(8)));

__device__ __forceinline__ unsigned short f2bf(float f) {
  unsigned u = __float_as_uint(f);
  unsigned r = (u + 0x7fffu + ((u >> 16) & 1u)) >> 16;
  return (unsigned short)r;
}
__device__ __forceinline__ float bf2f(unsigned short h) {
  return __uint_as_float(((unsigned)h) << 16);
}

// ---------------- fp32 -> bf16 conversion ----------------
__global__ __launch_bounds__(256) void k_cvt(const float* __restrict__ in,
                                             unsigned short* __restrict__ out, int n4) {
  int i = blockIdx.x * 256 + threadIdx.x;
  if (i < n4) {
    float4 v = ((const float4*)in)[i];
    ushort4 o;
    o.x = f2bf(v.x); o.y = f2bf(v.y); o.z = f2bf(v.z); o.w = f2bf(v.w);
    ((ushort4*)out)[i] = o;
  }
}

// ---------------- softmax over freq_w[513] ----------------
__global__ __launch_bounds__(256) void k_softmax(const float* __restrict__ fw,
                                                 float* __restrict__ wspec) {
  __shared__ float red[4];
  int tid = threadIdx.x;
  float m = -1e30f;
  for (int i = tid; i < 513; i += 256) m = fmaxf(m, fw[i]);
  #pragma unroll
  for (int o = 32; o; o >>= 1) m = fmaxf(m, __shfl_down(m, o));
  if ((tid & 63) == 0) red[tid >> 6] = m;
  __syncthreads();
  m = fmaxf(fmaxf(red[0], red[1]), fmaxf(red[2], red[3]));
  float s = 0.f;
  for (int i = tid; i < 513; i += 256) s += expf(fw[i] - m);
  #pragma unroll
  for (int o = 32; o; o >>= 1) s += __shfl_down(s, o);
  __syncthreads();
  if ((tid & 63) == 0) red[tid >> 6] = s;
  __syncthreads();
  s = red[0] + red[1] + red[2] + red[3];
  float inv = 1.f / s;
  for (int i = tid; i < 513; i += 256) wspec[i] = expf(fw[i] - m) * inv;
}

// ---------------- s = irfft(wspec), length 1024 ----------------
// s[d] = (1/1024) * ( w0 + (-1)^d * w512 + 2 * sum_{f=1..511} w_f cos(2*pi*f*d/1024) )
// 8 threads per d, f strided by 8; angle reduced mod 1024 in integers (exact).
__global__ __launch_bounds__(256) void k_s(const float* __restrict__ wspec,
                                           float* __restrict__ s) {
  int gid = blockIdx.x * 256 + threadIdx.x;   // 8192 threads
  int d = gid >> 3;
  int chunk = gid & 7;
  float acc = 0.f;
  for (int f = 1 + chunk; f < 512; f += 8) {
    int p = (f * d) & 1023;
    acc += wspec[f] * __cosf(6.283185307179586f * (float)p * (1.f / 1024.f));
  }
  acc += __shfl_xor(acc, 1);
  acc += __shfl_xor(acc, 2);
  acc += __shfl_xor(acc, 4);
  if (chunk == 0) {
    float w0 = wspec[0], w512 = wspec[512];
    float tot = w0 + ((d & 1) ? -w512 : w512) + 2.f * acc;
    s[d] = tot * (1.f / 1024.f);
  }
}

// ---------------- fill circulant Sb[n,k] = bf16(s[(k-n) mod 1024]) ----------------
__global__ __launch_bounds__(256) void k_sfill(const float* __restrict__ s,
                                               unsigned short* __restrict__ Sb) {
  int idx = blockIdx.x * 256 + threadIdx.x;   // 262144 ushort4's
  int n = idx >> 8;
  int k0 = (idx & 255) * 4;
  ushort4 o;
  o.x = f2bf(s[(k0 + 0 - n) & 1023]);
  o.y = f2bf(s[(k0 + 1 - n) & 1023]);
  o.z = f2bf(s[(k0 + 2 - n) & 1023]);
  o.w = f2bf(s[(k0 + 3 - n) & 1023]);
  ((ushort4*)Sb)[idx] = o;
}

// ---------------- block reduction helper ----------------
__device__ __forceinline__ float blk_sum(float v, float* red, int tid) {
  #pragma unroll
  for (int o = 32; o; o >>= 1) v += __shfl_down(v, o);
  __syncthreads();
  if ((tid & 63) == 0) red[tid >> 6] = v;
  __syncthreads();
  return red[0] + red[1] + red[2] + red[3];
}

// ---------------- per-row LayerNorm, in place (bf16 -> bf16) ----------------
__global__ __launch_bounds__(256) void k_ln(unsigned short* __restrict__ comp,
                                            const float* __restrict__ ln_g,
                                            const float* __restrict__ ln_b) {
  __shared__ float red[4];
  const int tid = threadIdx.x;
  const size_t rowoff = (size_t)blockIdx.x * 1024;
  ushort4 cv = ((const ushort4*)(comp + rowoff))[tid];
  float x0 = bf2f(cv.x), x1 = bf2f(cv.y), x2 = bf2f(cv.z), x3 = bf2f(cv.w);
  float mu = blk_sum(x0 + x1 + x2 + x3, red, tid) * (1.f / 1024.f);
  float d0 = x0 - mu, d1 = x1 - mu, d2 = x2 - mu, d3 = x3 - mu;
  float var = blk_sum(d0 * d0 + d1 * d1 + d2 * d2 + d3 * d3, red, tid) * (1.f / 1024.f);
  float inv = rsqrtf(var + 1e-5f);
  float4 g = ((const float4*)ln_g)[tid];
  float4 b = ((const float4*)ln_b)[tid];
  ushort4 o;
  o.x = f2bf(d0 * inv * g.x + b.x);
  o.y = f2bf(d1 * inv * g.y + b.y);
  o.z = f2bf(d2 * inv * g.z + b.z);
  o.w = f2bf(d3 * inv * g.w + b.w);
  ((ushort4*)(comp + rowoff))[tid] = o;
}

// ---------------- per-row Poincare scalar gamma ----------------
__global__ __launch_bounds__(256) void k_gamma(const unsigned short* __restrict__ flat,
                                               const float* __restrict__ t_ptr,
                                               float* __restrict__ gam) {
  __shared__ float red[4];
  const int tid = threadIdx.x;
  const size_t rowoff = (size_t)blockIdx.x * 1024;
  ushort4 cv = ((const ushort4*)(flat + rowoff))[tid];
  float f0 = bf2f(cv.x), f1 = bf2f(cv.y), f2 = bf2f(cv.z), f3 = bf2f(cv.w);
  float U2 = blk_sum(f0 * f0 + f1 * f1 + f2 * f2 + f3 * f3, red, tid);
  if (tid == 0) {
    const float tv = t_ptr[0];
    const float sc = 0.01f;      // sqrt(1e-4)
    const float c = 1e-4f;
    float nrm = sqrtf(U2);
    float nu = fmaxf(nrm, 1e-7f);
    float su = fminf(fmaxf(sc * nu, 1e-7f), 1.f - 1e-5f);
    float Af = tanhf((1.f - tv) * atanhf(su)) / (sc * nu);
    float nvn = fmaxf(fabsf(tv) * nrm, 1e-7f);
    float svv = fminf(fmaxf(sc * nvn, 1e-7f), 1.f - 1e-5f);
    float Bf = tv * tanhf(tv * atanhf(svv)) / (sc * nvn);
    float x2s = Af * Af * U2, y2s = Bf * Bf * U2, xys = Af * Bf * U2;
    float numc = (1.f + 2.f * c * xys + c * y2s) * Af + (1.f - c * x2s) * Bf;
    float den = fmaxf(1.f + 2.f * c * xys + c * c * x2s * y2s, 1e-7f);
    gam[blockIdx.x] = numc / den;
  }
}

// ---------------- bf16 MFMA GEMM: C[m,n] = sum_k A[m,k]*B[n,k] ----------------
// M=8192, N=1024, K=1024; grid 512 = 64 m-tiles x 8 n-tiles.
// MODE 0: silu -> bf16. MODE 1: plain -> bf16. MODE 2: gam[m]*scale -> fp32.
template <int MODE>
__global__ __launch_bounds__(256) void k_gemm(const unsigned short* __restrict__ A,
                                              const unsigned short* __restrict__ B,
                                              void* __restrict__ Cout,
                                              const float* __restrict__ scale_ptr,
                                              const float* __restrict__ gam_ptr) {
  __shared__ __align__(16) unsigned short As[128 * 64];
  __shared__ __align__(16) unsigned short Bs[128 * 64];
  const int tid = threadIdx.x;
  const int lane = tid & 63;
  const int wave = tid >> 6;
  const int bm = (blockIdx.x >> 3) * 128;
  const int bn = (blockIdx.x & 7) * 128;
  const int mhalf = (wave & 1) * 64;
  const int nhalf = (wave >> 1) * 64;
  f32x4 acc[4][4] = {};

  const int ar = tid >> 3;        // row within a 32-row staging round
  const int ac = (tid & 7) * 8;   // bf16 element offset within row
  const unsigned short* Abase = A + (size_t)(bm + ar) * 1024 + ac;
  const unsigned short* Bbase = B + (size_t)(bn + ar) * 1024 + ac;
  char* AsB = (char*)As;
  char* BsB = (char*)Bs;

  for (int kt = 0; kt < 16; ++kt) {
    const int k0 = kt * 64;
    #pragma unroll
    for (int r = 0; r < 4; ++r) {
      __builtin_amdgcn_global_load_lds(
          (const __attribute__((address_space(1))) void*)(Abase + (size_t)(r * 32) * 1024 + k0),
          (__attribute__((address_space(3))) void*)(AsB + r * 4096 + wave * 1024), 16, 0, 0);
      __builtin_amdgcn_global_load_lds(
          (const __attribute__((address_space(1))) void*)(Bbase + (size_t)(r * 32) * 1024 + k0),
          (__attribute__((address_space(3))) void*)(BsB + r * 4096 + wave * 1024), 16, 0, 0);
    }
    __syncthreads();
    const int mrow = lane & 15;
    const int kq = lane >> 4;
    #pragma unroll
    for (int kc = 0; kc < 2; ++kc) {
      bf16x8 af[4], bfr[4];
      #pragma unroll
      for (int mt = 0; mt < 4; ++mt)
        af[mt] = *(const bf16x8*)(AsB + (mhalf + mt * 16 + mrow) * 128 + kc * 64 + kq * 16);
      #pragma unroll
      for (int nt = 0; nt < 4; ++nt)
        bfr[nt] = *(const bf16x8*)(BsB + (nhalf + nt * 16 + mrow) * 128 + kc * 64 + kq * 16);
      #pragma unroll
      for (int mt = 0; mt < 4; ++mt)
        #pragma unroll
        for (int nt = 0; nt < 4; ++nt)
          acc[mt][nt] = __builtin_amdgcn_mfma_f32_16x16x32_bf16(af[mt], bfr[nt], acc[mt][nt], 0, 0, 0);
    }
    __syncthreads();
  }

  const float scl = (MODE == 2) ? scale_ptr[0] : 0.f;
  const int col = bn + nhalf + (lane & 15);
  const int rbase = bm + mhalf + (lane >> 4) * 4;
  #pragma unroll
  for (int mt = 0; mt < 4; ++mt)
    #pragma unroll
    for (int r = 0; r < 4; ++r) {
      const int row = rbase + mt * 16 + r;
      float rowscl = (MODE == 2) ? gam_ptr[row] * scl : 0.f;
      #pragma unroll
      for (int nt = 0; nt < 4; ++nt) {
        float v = acc[mt][nt][r];
        size_t idx = (size_t)row * 1024 + (col + nt * 16);
        if (MODE == 0) {
          float sv = v / (1.f + expf(-v));
          ((unsigned short*)Cout)[idx] = f2bf(sv);
        } else if (MODE == 1) {
          ((unsigned short*)Cout)[idx] = f2bf(v);
        } else {
          ((float*)Cout)[idx] = v * rowscl;
        }
      }
    }
}

extern "C" void kernel_launch(void* const* d_in, const int* in_sizes, int n_in,
                              void* d_out, int out_size, void* d_ws, size_t ws_size,
                              hipStream_t stream) {
  const float* x      = (const float*)d_in[0];
  const float* proj_w = (const float*)d_in[1];
  const float* ln_g   = (const float*)d_in[2];
  const float* ln_b   = (const float*)d_in[3];
  const float* freq_w = (const float*)d_in[4];
  const float* t_p    = (const float*)d_in[5];
  const float* down_w = (const float*)d_in[6];
  const float* scale  = (const float*)d_in[7];

  char* ws = (char*)d_ws;
  unsigned short* xb   = (unsigned short*)ws;               // 16 MB; reused for flat
  unsigned short* pwb  = (unsigned short*)(ws + 16777216);  // 2 MB; reused for Sb
  unsigned short* dwb  = (unsigned short*)(ws + 18874368);  // 2 MB
  unsigned short* comp = (unsigned short*)(ws + 20971520);  // 16 MB (LN in place)
  float* wspec         = (float*)(ws + 37748736);           // 2 KB
  float* s_buf         = (float*)(ws + 37748736 + 4096);    // 4 KB
  float* gam           = (float*)(ws + 37748736 + 8192);    // 32 KB
  unsigned short* flat = xb;
  unsigned short* Sb   = pwb;

  k_softmax<<<1, 256, 0, stream>>>(freq_w, wspec);
  k_s<<<32, 256, 0, stream>>>(wspec, s_buf);
  k_cvt<<<8192, 256, 0, stream>>>(x, xb, 2097152);
  k_cvt<<<1024, 256, 0, stream>>>(proj_w, pwb, 262144);
  k_cvt<<<1024, 256, 0, stream>>>(down_w, dwb, 262144);
  k_gemm<0><<<512, 256, 0, stream>>>(xb, pwb, (void*)comp, nullptr, nullptr);
  k_sfill<<<1024, 256, 0, stream>>>(s_buf, Sb);             // pwb dead after GEMM1
  k_ln<<<8192, 256, 0, stream>>>(comp, ln_g, ln_b);
  k_gemm<1><<<512, 256, 0, stream>>>(comp, Sb, (void*)flat, nullptr, nullptr);
  k_gamma<<<8192, 256, 0, stream>>>(flat, t_p, gam);
  k_gemm<2><<<512, 256, 0, stream>>>(flat, dwb, d_out, scale, gam);
}